// Round 8
// baseline (235.146 us; speedup 1.0000x reference)
//
#include <hip/hip_runtime.h>

typedef __attribute__((ext_vector_type(8))) short short8;
typedef __attribute__((ext_vector_type(4))) float f32x4;
typedef __attribute__((ext_vector_type(16))) float f32x16;

// Problem dims
#define BDIM 4096
#define INDIM 1024
#define HDIM 2048
#define KDIM 3072   // IN + H
#define NDIM 8192   // 4*H
#define OUT_HALF 8388608  // 4096*2048
#define NKT 96      // K-tiles of 32
#define ACHUNKS 1572864

__device__ __forceinline__ unsigned short f2bf(float f) {
  unsigned u = __float_as_uint(f);
  u += 0x7FFFu + ((u >> 16) & 1u);
  return (unsigned short)(u >> 16);
}

__device__ __forceinline__ float sigmoidf_(float x) {
  return 1.0f / (1.0f + __expf(-x));
}

// Merged pack: A = [x|h] bf16 [4096][3072]; W' gate-interleaved bf16 [8192][3072];
// bias[n'] = b_ih + b_hh.
__global__ __launch_bounds__(256) void pack_all(
    const float* __restrict__ x, const float* __restrict__ hh,
    const float* __restrict__ w_ih, const float* __restrict__ w_hh,
    const float* __restrict__ b_ih, const float* __restrict__ b_hh,
    unsigned short* __restrict__ A, unsigned short* __restrict__ W,
    float* __restrict__ bias) {
  int idx = blockIdx.x * 256 + threadIdx.x;
  if (idx < ACHUNKS) {
    int m = idx / 384;
    int k0 = (idx - m * 384) * 8;
    const float* src = (k0 < INDIM) ? (x + (size_t)m * INDIM + k0)
                                    : (hh + (size_t)m * HDIM + (k0 - INDIM));
    float4 lo = ((const float4*)src)[0];
    float4 hi = ((const float4*)src)[1];
    union { unsigned short us[8]; uint4 v; } o;
    o.us[0] = f2bf(lo.x); o.us[1] = f2bf(lo.y); o.us[2] = f2bf(lo.z); o.us[3] = f2bf(lo.w);
    o.us[4] = f2bf(hi.x); o.us[5] = f2bf(hi.y); o.us[6] = f2bf(hi.z); o.us[7] = f2bf(hi.w);
    *(uint4*)(A + (size_t)m * KDIM + k0) = o.v;
  } else {
    idx -= ACHUNKS;
    int np = idx / 384;
    int rem = idx - np * 384;
    int k0 = rem * 8;
    int j = np >> 2;
    int g = np & 3;
    int n = g * HDIM + j;
    const float* src = (k0 < INDIM) ? (w_ih + (size_t)n * INDIM + k0)
                                    : (w_hh + (size_t)n * HDIM + (k0 - INDIM));
    float4 lo = ((const float4*)src)[0];
    float4 hi = ((const float4*)src)[1];
    union { unsigned short us[8]; uint4 v; } o;
    o.us[0] = f2bf(lo.x); o.us[1] = f2bf(lo.y); o.us[2] = f2bf(lo.z); o.us[3] = f2bf(lo.w);
    o.us[4] = f2bf(hi.x); o.us[5] = f2bf(hi.y); o.us[6] = f2bf(hi.z); o.us[7] = f2bf(hi.w);
    *(uint4*)(W + (size_t)np * KDIM + k0) = o.v;
    if (rem == 0) bias[np] = b_ih[n] + b_hh[n];
  }
}

__device__ __forceinline__ void gload_lds16(const void* g, void* l) {
  __builtin_amdgcn_global_load_lds(
      (const __attribute__((address_space(1))) void*)g,
      (__attribute__((address_space(3))) void*)l, 16, 0, 0);
}

#define SB0 __builtin_amdgcn_sched_barrier(0)

// 256x256 tile, BK=32, 8 waves (2Mx4N), 4-deep LDS ring (4 x 32KiB),
// row-pair XOR swizzle (T2), counted vmcnt (T4), setprio (T5), R4's
// 1-barrier-per-K-tile pipelined schedule, mfma_f32_32x32x16_bf16.
// Per wave: 128x64 = 4 m-tiles x 2 n-tiles of 32x32; 2 k-halves per BK=32.
__global__ __launch_bounds__(512, 2) void lstm_gemm(
    const unsigned short* __restrict__ A,
    const unsigned short* __restrict__ W,
    const float* __restrict__ bias,
    const float* __restrict__ c,
    float* __restrict__ out) {
  extern __shared__ char smem[];  // 131072 bytes

  const int tid = threadIdx.x;
  const int lane = tid & 63;
  const int wid = tid >> 6;

  // XCD swizzle (R4's): xcd owns 2 tm slabs; tn sweeps slowest. Bijective/512.
  const int bid = blockIdx.x;
  const int local = bid >> 3;
  const int tm = (bid & 7) * 2 + (local & 1);   // 0..15
  const int tn = local >> 1;                    // 0..31

  // ---- staging source decode (inverse swizzle, rule #21; R4-verified) ----
  int rowA0, clA0, rowA1, clA1;
  {
    int P0 = wid * 1024 + lane * 16;
    int P1 = 8192 + wid * 1024 + lane * 16;
    int r2, cp, cg;
    r2 = P0 >> 7; cp = (P0 >> 4) & 7; cg = cp ^ (r2 & 7);
    rowA0 = r2 * 2 + (cg >> 2); clA0 = cg & 3;
    r2 = P1 >> 7; cp = (P1 >> 4) & 7; cg = cp ^ (r2 & 7);
    rowA1 = r2 * 2 + (cg >> 2); clA1 = cg & 3;
  }
  const unsigned short* gA0 = A + (size_t)(tm * 256 + rowA0) * KDIM + clA0 * 8;
  const unsigned short* gA1 = A + (size_t)(tm * 256 + rowA1) * KDIM + clA1 * 8;
  const unsigned short* gB0 = W + (size_t)(tn * 256 + rowA0) * KDIM + clA0 * 8;
  const unsigned short* gB1 = W + (size_t)(tn * 256 + rowA1) * KDIM + clA1 * 8;
  const int ldA0 = wid * 1024;
  const int ldA1 = 8192 + wid * 1024;
  const int ldB0 = 16384 + wid * 1024;
  const int ldB1 = 24576 + wid * 1024;

  // ---- ds_read per-lane constants (swizzled, 32x32 frag layout) ----
  // Frag (A or B): lane holds row/col r5=lane&31, k-chunk kb=lane>>5 (8 bf16).
  // Logical chunk c = kh*2+kb; phys cp = ((r5&1)*4 + c) ^ ((r5>>1)&7).
  const int r5 = lane & 31;
  const int kb = lane >> 5;
  const int wr = wid >> 2;    // 0..1 (M half)
  const int wc = wid & 3;     // 0..3 (N quarter)
  int aoff[2];
#pragma unroll
  for (int kh = 0; kh < 2; ++kh) {
    int cp = (((r5 & 1) << 2) + kh * 2 + kb) ^ ((r5 >> 1) & 7);
    aoff[kh] = (r5 >> 1) * 128 + cp * 16;
  }
  const int abase = wr * 8192;            // + mt*2048 + aoff[kh]
  const int bbase = 16384 + wc * 4096;    // + nt*2048 + aoff[kh]  (wc*64 rows x 64B)

  f32x16 acc[4][2] = {};
  short8 af[4], ag[4], bf_[2][2];

  // ---- prologue: stage tiles 0,1,2 into bufs 0,1,2 ----
#pragma unroll
  for (int tt = 0; tt < 3; ++tt) {
    char* lb = smem + tt * 32768;
    gload_lds16(gA0, lb + ldA0);
    gload_lds16(gA1, lb + ldA1);
    gload_lds16(gB0, lb + ldB0);
    gload_lds16(gB1, lb + ldB1);
    gA0 += 32; gA1 += 32; gB0 += 32; gB1 += 32;
  }
  asm volatile("s_waitcnt vmcnt(8)" ::: "memory");   // tile 0 landed
  __builtin_amdgcn_s_barrier(); SB0;
  // issue af(0) [kh0], bf_(0) [both kh]
#pragma unroll
  for (int mt = 0; mt < 4; ++mt)
    af[mt] = *(const short8*)(smem + abase + mt * 2048 + aoff[0]);
#pragma unroll
  for (int nt = 0; nt < 2; ++nt)
#pragma unroll
    for (int kh = 0; kh < 2; ++kh)
      bf_[nt][kh] = *(const short8*)(smem + bbase + nt * 2048 + aoff[kh]);

// Tile body (R4 rhythm). Entry: af(T) kh0 + bf_(T) issued; vm queue = 8.
#define TILE_BODY(T, VMSTR, STAGE_, PREF_)                                   \
  do {                                                                       \
    const char* rb = smem + ((T) & 3) * 32768;                               \
    const char* rbn = smem + (((T) + 1) & 3) * 32768;                        \
    char* lb = smem + (((T) + 3) & 3) * 32768;                               \
    if (STAGE_) {                                                            \
      gload_lds16(gA0, lb + ldA0);                                           \
      gload_lds16(gA1, lb + ldA1);                                           \
    }                                                                        \
    _Pragma("unroll")                                                        \
    for (int mt = 0; mt < 4; ++mt)                                           \
      ag[mt] = *(const short8*)(rb + abase + mt * 2048 + aoff[1]);           \
    SB0;                                                                     \
    __builtin_amdgcn_s_setprio(1);                                           \
    _Pragma("unroll")                                                        \
    for (int mt = 0; mt < 4; ++mt)                                           \
      _Pragma("unroll")                                                      \
      for (int nt = 0; nt < 2; ++nt)                                         \
        acc[mt][nt] = __builtin_amdgcn_mfma_f32_32x32x16_bf16(               \
            af[mt], bf_[nt][0], acc[mt][nt], 0, 0, 0);                       \
    __builtin_amdgcn_s_setprio(0);                                           \
    if (STAGE_) {                                                            \
      gload_lds16(gB0, lb + ldB0);                                           \
      gload_lds16(gB1, lb + ldB1);                                           \
      gA0 += 32; gA1 += 32; gB0 += 32; gB1 += 32;                            \
    }                                                                        \
    asm volatile("s_waitcnt vmcnt(" VMSTR ")" ::: "memory");                 \
    asm volatile("s_waitcnt lgkmcnt(0)" ::: "memory");                       \
    __builtin_amdgcn_s_barrier(); SB0;                                       \
    if (PREF_) {                                                             \
      _Pragma("unroll")                                                      \
      for (int mt = 0; mt < 4; ++mt)                                         \
        af[mt] = *(const short8*)(rbn + abase + mt * 2048 + aoff[0]);        \
    }                                                                        \
    SB0;                                                                     \
    __builtin_amdgcn_s_setprio(1);                                           \
    _Pragma("unroll")                                                        \
    for (int mt = 0; mt < 4; ++mt)                                           \
      _Pragma("unroll")                                                      \
      for (int nt = 0; nt < 2; ++nt)                                         \
        acc[mt][nt] = __builtin_amdgcn_mfma_f32_32x32x16_bf16(               \
            ag[mt], bf_[nt][1], acc[mt][nt], 0, 0, 0);                       \
    __builtin_amdgcn_s_setprio(0);                                           \
    if (PREF_) {                                                             \
      _Pragma("unroll")                                                      \
      for (int nt = 0; nt < 2; ++nt)                                         \
        _Pragma("unroll")                                                    \
        for (int kh = 0; kh < 2; ++kh)                                       \
          bf_[nt][kh] = *(const short8*)(rbn + bbase + nt * 2048 + aoff[kh]);\
    }                                                                        \
  } while (0)

  for (int t = 0; t < NKT - 3; ++t) TILE_BODY(t, "8", true, true);
  TILE_BODY(NKT - 3, "4", false, true);
  TILE_BODY(NKT - 2, "0", false, true);
  TILE_BODY(NKT - 1, "0", false, false);
#undef TILE_BODY

  // ---- fused LSTM epilogue (32x32 C-layout, m74/m101) ----
  // acc[mt][nt] reg r, lane l -> gates row (r&3)+8*(r>>2)+4*kb (0..31),
  // col nt*32 + r5 (0..63 within wave). Wave-private LDS bounce:
  // [32 rows][stride 68 floats], 8704 B/wave (<= 69632 total, clear of buf3
  // which the final K-tile read; waves only touch their own region).
  const int jr = lane & 15;               // j within wave's 16
  const int rowg = lane >> 4;             // 0..3
  const f32x4 bi = *(const f32x4*)(bias + tn * 256 + wc * 64 + jr * 4);
  float* ep = (float*)smem + wid * 2176;

#pragma unroll
  for (int mt = 0; mt < 4; ++mt) {
#pragma unroll
    for (int nt = 0; nt < 2; ++nt)
#pragma unroll
      for (int r = 0; r < 16; ++r)
        ep[((r & 3) + 8 * (r >> 2) + 4 * kb) * 68 + nt * 32 + r5] = acc[mt][nt][r];
    asm volatile("s_waitcnt lgkmcnt(0)" ::: "memory");
#pragma unroll
    for (int t4 = 0; t4 < 8; ++t4) {
      const int row = rowg + t4 * 4;       // 0..31
      f32x4 g4 = *(const f32x4*)(ep + row * 68 + jr * 4);
      const float f_in = g4[0] + bi[0];
      const float i_in = g4[1] + bi[1];
      const float ic_in = g4[2] + bi[2];
      const float o_in = g4[3] + bi[3];
      const float ft = sigmoidf_(f_in);
      const float it = sigmoidf_(i_in);
      const float ics = __sinf(ic_in);
      const int mg = tm * 256 + wr * 128 + mt * 32 + row;
      const int jg = tn * 64 + wc * 16 + jr;
      const float cv = c[(size_t)mg * HDIM + jg];
      const float ct = cv * ft + ics * it;
      const float ot = sigmoidf_(o_in);
      const float ht = ot * __sinf(ct);
      out[(size_t)mg * HDIM + jg] = ht;
      out[OUT_HALF + (size_t)mg * HDIM + jg] = ct;
    }
    asm volatile("s_waitcnt lgkmcnt(0)" ::: "memory");
  }
}

extern "C" void kernel_launch(void* const* d_in, const int* in_sizes, int n_in,
                              void* d_out, int out_size, void* d_ws, size_t ws_size,
                              hipStream_t stream) {
  const float* x    = (const float*)d_in[0];
  const float* h    = (const float*)d_in[1];
  const float* c    = (const float*)d_in[2];
  const float* w_ih = (const float*)d_in[3];
  const float* w_hh = (const float*)d_in[4];
  const float* b_ih = (const float*)d_in[5];
  const float* b_hh = (const float*)d_in[6];
  float* out = (float*)d_out;

  char* ws = (char*)d_ws;
  unsigned short* Abf = (unsigned short*)ws;                       // 25,165,824 B
  unsigned short* Wbf = (unsigned short*)(ws + 25165824);          // 50,331,648 B
  float* bias = (float*)(ws + 25165824 + 50331648);                // 32,768 B

  hipFuncSetAttribute((const void*)lstm_gemm,
                      hipFuncAttributeMaxDynamicSharedMemorySize, 131072);

  pack_all<<<18432, 256, 0, stream>>>(x, h, w_ih, w_hh, b_ih, b_hh, Abf, Wbf, bias);
  lstm_gemm<<<512, 512, 131072, stream>>>(Abf, Wbf, bias, c, out);
}

// Round 9
// 223.007 us; speedup vs baseline: 1.0544x; 1.0544x over previous
//
#include <hip/hip_runtime.h>

typedef __attribute__((ext_vector_type(8))) short short8;
typedef __attribute__((ext_vector_type(4))) float f32x4;

// Problem dims
#define BDIM 4096
#define INDIM 1024
#define HDIM 2048
#define KDIM 3072   // IN + H
#define NDIM 8192   // 4*H
#define OUT_HALF 8388608  // 4096*2048
#define NKT 96      // K-tiles of 32
#define ACHUNKS 1572864

__device__ __forceinline__ unsigned short f2bf(float f) {
  unsigned u = __float_as_uint(f);
  u += 0x7FFFu + ((u >> 16) & 1u);
  return (unsigned short)(u >> 16);
}

__device__ __forceinline__ float sigmoidf_(float x) {
  return 1.0f / (1.0f + __expf(-x));
}

// Merged pack: A = [x|h] bf16 [4096][3072]; W' gate-interleaved bf16 [8192][3072];
// bias[n'] = b_ih + b_hh.
__global__ __launch_bounds__(256) void pack_all(
    const float* __restrict__ x, const float* __restrict__ hh,
    const float* __restrict__ w_ih, const float* __restrict__ w_hh,
    const float* __restrict__ b_ih, const float* __restrict__ b_hh,
    unsigned short* __restrict__ A, unsigned short* __restrict__ W,
    float* __restrict__ bias) {
  int idx = blockIdx.x * 256 + threadIdx.x;
  if (idx < ACHUNKS) {
    int m = idx / 384;
    int k0 = (idx - m * 384) * 8;
    const float* src = (k0 < INDIM) ? (x + (size_t)m * INDIM + k0)
                                    : (hh + (size_t)m * HDIM + (k0 - INDIM));
    float4 lo = ((const float4*)src)[0];
    float4 hi = ((const float4*)src)[1];
    union { unsigned short us[8]; uint4 v; } o;
    o.us[0] = f2bf(lo.x); o.us[1] = f2bf(lo.y); o.us[2] = f2bf(lo.z); o.us[3] = f2bf(lo.w);
    o.us[4] = f2bf(hi.x); o.us[5] = f2bf(hi.y); o.us[6] = f2bf(hi.z); o.us[7] = f2bf(hi.w);
    *(uint4*)(A + (size_t)m * KDIM + k0) = o.v;
  } else {
    idx -= ACHUNKS;
    int np = idx / 384;
    int rem = idx - np * 384;
    int k0 = rem * 8;
    int j = np >> 2;
    int g = np & 3;
    int n = g * HDIM + j;
    const float* src = (k0 < INDIM) ? (w_ih + (size_t)n * INDIM + k0)
                                    : (w_hh + (size_t)n * HDIM + (k0 - INDIM));
    float4 lo = ((const float4*)src)[0];
    float4 hi = ((const float4*)src)[1];
    union { unsigned short us[8]; uint4 v; } o;
    o.us[0] = f2bf(lo.x); o.us[1] = f2bf(lo.y); o.us[2] = f2bf(lo.z); o.us[3] = f2bf(lo.w);
    o.us[4] = f2bf(hi.x); o.us[5] = f2bf(hi.y); o.us[6] = f2bf(hi.z); o.us[7] = f2bf(hi.w);
    *(uint4*)(W + (size_t)np * KDIM + k0) = o.v;
    if (rem == 0) bias[np] = b_ih[n] + b_hh[n];
  }
}

__device__ __forceinline__ void gload_lds16(const void* g, void* l) {
  __builtin_amdgcn_global_load_lds(
      (const __attribute__((address_space(1))) void*)g,
      (__attribute__((address_space(3))) void*)l, 16, 0, 0);
}

#define SB0 __builtin_amdgcn_sched_barrier(0)

// 256x256 tile, BK=32, 8 waves (2Mx4N), 4-deep LDS ring (4 x 32KiB),
// row-pair XOR swizzle (T2), counted vmcnt (T4), setprio (T5), R4's
// 1-barrier-per-K-tile pipelined schedule + B-frag register ping-pong:
// af(T+1)+bfN(T+1) issue together right after the barrier (hidden under
// MFMA-B which consumes the OTHER bf set), mfma_f32_16x16x32_bf16.
__global__ __launch_bounds__(512, 2) void lstm_gemm(
    const unsigned short* __restrict__ A,
    const unsigned short* __restrict__ W,
    const float* __restrict__ bias,
    const float* __restrict__ c,
    float* __restrict__ out) {
  extern __shared__ char smem[];  // 131072 bytes

  const int tid = threadIdx.x;
  const int lane = tid & 63;
  const int wid = tid >> 6;

  // XCD swizzle: xcd owns 2 tm slabs; tn sweeps slowest. Bijective over 512.
  const int bid = blockIdx.x;
  const int local = bid >> 3;
  const int tm = (bid & 7) * 2 + (local & 1);   // 0..15
  const int tn = local >> 1;                    // 0..31

  // ---- staging source decode (inverse swizzle, rule #21; R4-verified) ----
  int rowA0, clA0, rowA1, clA1;
  {
    int P0 = wid * 1024 + lane * 16;
    int P1 = 8192 + wid * 1024 + lane * 16;
    int r2, cp, cg;
    r2 = P0 >> 7; cp = (P0 >> 4) & 7; cg = cp ^ (r2 & 7);
    rowA0 = r2 * 2 + (cg >> 2); clA0 = cg & 3;
    r2 = P1 >> 7; cp = (P1 >> 4) & 7; cg = cp ^ (r2 & 7);
    rowA1 = r2 * 2 + (cg >> 2); clA1 = cg & 3;
  }
  const unsigned short* gA0 = A + (size_t)(tm * 256 + rowA0) * KDIM + clA0 * 8;
  const unsigned short* gA1 = A + (size_t)(tm * 256 + rowA1) * KDIM + clA1 * 8;
  const unsigned short* gB0 = W + (size_t)(tn * 256 + rowA0) * KDIM + clA0 * 8;
  const unsigned short* gB1 = W + (size_t)(tn * 256 + rowA1) * KDIM + clA1 * 8;
  const int ldA0 = wid * 1024;
  const int ldA1 = 8192 + wid * 1024;
  const int ldB0 = 16384 + wid * 1024;
  const int ldB1 = 24576 + wid * 1024;

  // ---- ds_read per-lane constants (swizzled; R4-verified) ----
  const int fr = lane & 15;
  const int fq = lane >> 4;
  const int wr = wid >> 2;
  const int wc = wid & 3;
  const int frh = fr >> 1;
  const int clA = (((fr & 1) << 2) | fq) ^ frh;
  const int aconst = wr * 8192 + frh * 128 + clA * 16;
  const int bconst = 16384 + wc * 4096 + frh * 128 + clA * 16;

  f32x4 acc[8][4] = {};
  short8 af[4], ag[4], bfA[4], bfB[4];

  // ---- prologue: stage tiles 0,1,2 into bufs 0,1,2 ----
#pragma unroll
  for (int tt = 0; tt < 3; ++tt) {
    char* lb = smem + tt * 32768;
    gload_lds16(gA0, lb + ldA0);
    gload_lds16(gA1, lb + ldA1);
    gload_lds16(gB0, lb + ldB0);
    gload_lds16(gB1, lb + ldB1);
    gA0 += 32; gA1 += 32; gB0 += 32; gB1 += 32;
  }
  asm volatile("s_waitcnt vmcnt(8)" ::: "memory");   // tile 0 landed
  __builtin_amdgcn_s_barrier(); SB0;
  // issue af(0), bfA(0) from buf0
#pragma unroll
  for (int mi = 0; mi < 4; ++mi)
    af[mi] = *(const short8*)(smem + aconst + mi * 1024);
#pragma unroll
  for (int ni = 0; ni < 4; ++ni)
    bfA[ni] = *(const short8*)(smem + bconst + ni * 1024);

// Tile body. Entry: af(T), BFC(T) issued; vm queue = stages for T+1,T+2 (8).
// Post-barrier: issue af(T+1)+BFN(T+1) together, hidden under MFMA-B (uses BFC).
#define TILE_BODY(T, VMSTR, STAGE_, PREF_, BFC, BFN)                         \
  do {                                                                       \
    const char* rb = smem + ((T) & 3) * 32768;                               \
    const char* rbn = smem + (((T) + 1) & 3) * 32768;                        \
    char* lb = smem + (((T) + 3) & 3) * 32768;                               \
    if (STAGE_) {                                                            \
      gload_lds16(gA0, lb + ldA0);                                           \
      gload_lds16(gA1, lb + ldA1);                                           \
    }                                                                        \
    _Pragma("unroll")                                                        \
    for (int mi = 0; mi < 4; ++mi)                                           \
      ag[mi] = *(const short8*)(rb + aconst + (mi + 4) * 1024);              \
    SB0;                                                                     \
    __builtin_amdgcn_s_setprio(1);                                           \
    _Pragma("unroll")                                                        \
    for (int mi = 0; mi < 4; ++mi)                                           \
      _Pragma("unroll")                                                      \
      for (int ni = 0; ni < 4; ++ni)                                         \
        acc[mi][ni] = __builtin_amdgcn_mfma_f32_16x16x32_bf16(               \
            af[mi], BFC[ni], acc[mi][ni], 0, 0, 0);                          \
    __builtin_amdgcn_s_setprio(0);                                           \
    if (STAGE_) {                                                            \
      gload_lds16(gB0, lb + ldB0);                                           \
      gload_lds16(gB1, lb + ldB1);                                           \
      gA0 += 32; gA1 += 32; gB0 += 32; gB1 += 32;                            \
    }                                                                        \
    asm volatile("s_waitcnt vmcnt(" VMSTR ") lgkmcnt(0)" ::: "memory");      \
    SB0;                                                                     \
    __builtin_amdgcn_s_barrier(); SB0;                                       \
    if (PREF_) {                                                             \
      _Pragma("unroll")                                                      \
      for (int mi = 0; mi < 4; ++mi)                                         \
        af[mi] = *(const short8*)(rbn + aconst + mi * 1024);                 \
      _Pragma("unroll")                                                      \
      for (int ni = 0; ni < 4; ++ni)                                         \
        BFN[ni] = *(const short8*)(rbn + bconst + ni * 1024);                \
    }                                                                        \
    SB0;                                                                     \
    __builtin_amdgcn_s_setprio(1);                                           \
    _Pragma("unroll")                                                        \
    for (int mi = 0; mi < 4; ++mi)                                           \
      _Pragma("unroll")                                                      \
      for (int ni = 0; ni < 4; ++ni)                                         \
        acc[mi + 4][ni] = __builtin_amdgcn_mfma_f32_16x16x32_bf16(           \
            ag[mi], BFC[ni], acc[mi + 4][ni], 0, 0, 0);                      \
    __builtin_amdgcn_s_setprio(0);                                           \
  } while (0)

  for (int t = 0; t < 92; t += 2) {
    TILE_BODY(t,     "8", true, true, bfA, bfB);
    TILE_BODY(t + 1, "8", true, true, bfB, bfA);
  }
  TILE_BODY(92, "8", true,  true,  bfA, bfB);
  TILE_BODY(93, "4", false, true,  bfB, bfA);
  TILE_BODY(94, "0", false, true,  bfA, bfB);
  TILE_BODY(95, "0", false, false, bfB, bfA);
#undef TILE_BODY

  // ---- fused LSTM epilogue ----
  // Wave-private LDS bounce, stride 68 floats (4608 B/wave; bufs 0-1 region,
  // final K-tile read buf 3 -> untouched).
  const int jw = fr;
  const int jg = tn * 64 + wc * 16 + jw;   // global j in [0,2048)
  const f32x4 bi = *(const f32x4*)(bias + tn * 256 + wc * 64 + jw * 4);
  float* ep = (float*)smem + wid * 1152;

#pragma unroll
  for (int mi = 0; mi < 8; ++mi) {
#pragma unroll
    for (int ni = 0; ni < 4; ++ni)
#pragma unroll
      for (int r = 0; r < 4; ++r)
        ep[(fq * 4 + r) * 68 + ni * 16 + fr] = acc[mi][ni][r];
    asm volatile("s_waitcnt lgkmcnt(0)" ::: "memory");
#pragma unroll
    for (int t4 = 0; t4 < 4; ++t4) {
      const int row = fq + t4 * 4;         // 0..15
      f32x4 g4 = *(const f32x4*)(ep + row * 68 + jw * 4);
      const float f_in = g4[0] + bi[0];
      const float i_in = g4[1] + bi[1];
      const float ic_in = g4[2] + bi[2];
      const float o_in = g4[3] + bi[3];
      const float ft = sigmoidf_(f_in);
      const float it = sigmoidf_(i_in);
      const float ics = __sinf(ic_in);
      const int mg = tm * 256 + wr * 128 + mi * 16 + row;
      const float cv = c[(size_t)mg * HDIM + jg];
      const float ct = cv * ft + ics * it;
      const float ot = sigmoidf_(o_in);
      const float ht = ot * __sinf(ct);
      out[(size_t)mg * HDIM + jg] = ht;
      out[OUT_HALF + (size_t)mg * HDIM + jg] = ct;
    }
    asm volatile("s_waitcnt lgkmcnt(0)" ::: "memory");
  }
}

extern "C" void kernel_launch(void* const* d_in, const int* in_sizes, int n_in,
                              void* d_out, int out_size, void* d_ws, size_t ws_size,
                              hipStream_t stream) {
  const float* x    = (const float*)d_in[0];
  const float* h    = (const float*)d_in[1];
  const float* c    = (const float*)d_in[2];
  const float* w_ih = (const float*)d_in[3];
  const float* w_hh = (const float*)d_in[4];
  const float* b_ih = (const float*)d_in[5];
  const float* b_hh = (const float*)d_in[6];
  float* out = (float*)d_out;

  char* ws = (char*)d_ws;
  unsigned short* Abf = (unsigned short*)ws;                       // 25,165,824 B
  unsigned short* Wbf = (unsigned short*)(ws + 25165824);          // 50,331,648 B
  float* bias = (float*)(ws + 25165824 + 50331648);                // 32,768 B

  hipFuncSetAttribute((const void*)lstm_gemm,
                      hipFuncAttributeMaxDynamicSharedMemorySize, 131072);

  pack_all<<<18432, 256, 0, stream>>>(x, h, w_ih, w_hh, b_ih, b_hh, Abf, Wbf, bias);
  lstm_gemm<<<512, 512, 131072, stream>>>(Abf, Wbf, bias, c, out);
}

// Round 10
// 218.986 us; speedup vs baseline: 1.0738x; 1.0184x over previous
//
#include <hip/hip_runtime.h>

typedef __attribute__((ext_vector_type(8))) short short8;
typedef __attribute__((ext_vector_type(4))) float f32x4;

// Problem dims
#define BDIM 4096
#define INDIM 1024
#define HDIM 2048
#define KDIM 3072   // IN + H
#define NDIM 8192   // 4*H
#define OUT_HALF 8388608  // 4096*2048
#define NKT 96      // K-tiles of 32
#define ACHUNKS 1572864

__device__ __forceinline__ unsigned short f2bf(float f) {
  unsigned u = __float_as_uint(f);
  u += 0x7FFFu + ((u >> 16) & 1u);
  return (unsigned short)(u >> 16);
}

__device__ __forceinline__ float sigmoidf_(float x) {
  return 1.0f / (1.0f + __expf(-x));
}

// Merged pack: A = [x|h] bf16 [4096][3072]; W' gate-interleaved bf16 [8192][3072];
// bias[n'] = b_ih + b_hh.
__global__ __launch_bounds__(256) void pack_all(
    const float* __restrict__ x, const float* __restrict__ hh,
    const float* __restrict__ w_ih, const float* __restrict__ w_hh,
    const float* __restrict__ b_ih, const float* __restrict__ b_hh,
    unsigned short* __restrict__ A, unsigned short* __restrict__ W,
    float* __restrict__ bias) {
  int idx = blockIdx.x * 256 + threadIdx.x;
  if (idx < ACHUNKS) {
    int m = idx / 384;
    int k0 = (idx - m * 384) * 8;
    const float* src = (k0 < INDIM) ? (x + (size_t)m * INDIM + k0)
                                    : (hh + (size_t)m * HDIM + (k0 - INDIM));
    float4 lo = ((const float4*)src)[0];
    float4 hi = ((const float4*)src)[1];
    union { unsigned short us[8]; uint4 v; } o;
    o.us[0] = f2bf(lo.x); o.us[1] = f2bf(lo.y); o.us[2] = f2bf(lo.z); o.us[3] = f2bf(lo.w);
    o.us[4] = f2bf(hi.x); o.us[5] = f2bf(hi.y); o.us[6] = f2bf(hi.z); o.us[7] = f2bf(hi.w);
    *(uint4*)(A + (size_t)m * KDIM + k0) = o.v;
  } else {
    idx -= ACHUNKS;
    int np = idx / 384;
    int rem = idx - np * 384;
    int k0 = rem * 8;
    int j = np >> 2;
    int g = np & 3;
    int n = g * HDIM + j;
    const float* src = (k0 < INDIM) ? (w_ih + (size_t)n * INDIM + k0)
                                    : (w_hh + (size_t)n * HDIM + (k0 - INDIM));
    float4 lo = ((const float4*)src)[0];
    float4 hi = ((const float4*)src)[1];
    union { unsigned short us[8]; uint4 v; } o;
    o.us[0] = f2bf(lo.x); o.us[1] = f2bf(lo.y); o.us[2] = f2bf(lo.z); o.us[3] = f2bf(lo.w);
    o.us[4] = f2bf(hi.x); o.us[5] = f2bf(hi.y); o.us[6] = f2bf(hi.z); o.us[7] = f2bf(hi.w);
    *(uint4*)(W + (size_t)np * KDIM + k0) = o.v;
    if (rem == 0) bias[np] = b_ih[n] + b_hh[n];
  }
}

__device__ __forceinline__ void gload_lds16(const void* g, void* l) {
  __builtin_amdgcn_global_load_lds(
      (const __attribute__((address_space(1))) void*)g,
      (__attribute__((address_space(3))) void*)l, 16, 0, 0);
}

#define SB0 __builtin_amdgcn_sched_barrier(0)

// R4-exact GEMM: 256x256 tile, BK=32, 8 waves (2Mx4N), 4-deep LDS ring
// (4 x 32KiB), row-pair XOR swizzle (T2), counted vmcnt (T4), setprio (T5),
// 1-barrier-per-K-tile pipelined schedule (af prefetch alone post-barrier,
// bf_ prefetch after MFMA-B), mfma_f32_16x16x32_bf16.
__global__ __launch_bounds__(512, 2) void lstm_gemm(
    const unsigned short* __restrict__ A,
    const unsigned short* __restrict__ W,
    const float* __restrict__ bias,
    const float* __restrict__ c,
    float* __restrict__ out) {
  extern __shared__ char smem[];  // 131072 bytes

  const int tid = threadIdx.x;
  const int lane = tid & 63;
  const int wid = tid >> 6;

  // XCD swizzle: xcd owns 2 tm slabs; tn sweeps slowest. Bijective over 512.
  const int bid = blockIdx.x;
  const int local = bid >> 3;
  const int tm = (bid & 7) * 2 + (local & 1);   // 0..15
  const int tn = local >> 1;                    // 0..31

  // ---- staging source decode (inverse swizzle, rule #21) ----
  int rowA0, clA0, rowA1, clA1;
  {
    int P0 = wid * 1024 + lane * 16;
    int P1 = 8192 + wid * 1024 + lane * 16;
    int r2, cp, cg;
    r2 = P0 >> 7; cp = (P0 >> 4) & 7; cg = cp ^ (r2 & 7);
    rowA0 = r2 * 2 + (cg >> 2); clA0 = cg & 3;
    r2 = P1 >> 7; cp = (P1 >> 4) & 7; cg = cp ^ (r2 & 7);
    rowA1 = r2 * 2 + (cg >> 2); clA1 = cg & 3;
  }
  const unsigned short* gA0 = A + (size_t)(tm * 256 + rowA0) * KDIM + clA0 * 8;
  const unsigned short* gA1 = A + (size_t)(tm * 256 + rowA1) * KDIM + clA1 * 8;
  const unsigned short* gB0 = W + (size_t)(tn * 256 + rowA0) * KDIM + clA0 * 8;
  const unsigned short* gB1 = W + (size_t)(tn * 256 + rowA1) * KDIM + clA1 * 8;
  const int ldA0 = wid * 1024;
  const int ldA1 = 8192 + wid * 1024;
  const int ldB0 = 16384 + wid * 1024;
  const int ldB1 = 24576 + wid * 1024;

  // ---- ds_read per-lane constants (swizzled) ----
  const int fr = lane & 15;
  const int fq = lane >> 4;
  const int wr = wid >> 2;    // 0..1 (rows)
  const int wc = wid & 3;     // 0..3 (cols)
  const int frh = fr >> 1;
  const int clA = (((fr & 1) << 2) | fq) ^ frh;
  const int aconst = wr * 8192 + frh * 128 + clA * 16;
  const int bconst = 16384 + wc * 4096 + frh * 128 + clA * 16;

  f32x4 acc[8][4] = {};
  short8 af[4], bf_[4], ag[4];

  // ---- prologue: stage tiles 0,1,2 ----
#pragma unroll
  for (int tt = 0; tt < 3; ++tt) {
    char* lb = smem + tt * 32768;
    gload_lds16(gA0, lb + ldA0);
    gload_lds16(gA1, lb + ldA1);
    gload_lds16(gB0, lb + ldB0);
    gload_lds16(gB1, lb + ldB1);
    gA0 += 32; gA1 += 32; gB0 += 32; gB1 += 32;
  }
  asm volatile("s_waitcnt vmcnt(8)" ::: "memory");   // tile 0 landed
  __builtin_amdgcn_s_barrier(); SB0;
  // issue af(0), bf_(0)
#pragma unroll
  for (int mi = 0; mi < 4; ++mi)
    af[mi] = *(const short8*)(smem + aconst + mi * 1024);
#pragma unroll
  for (int ni = 0; ni < 4; ++ni)
    bf_[ni] = *(const short8*)(smem + bconst + ni * 1024);

// Tile body. Entry: af(T),bf_(T) issued; vm queue = stages for T+1,T+2 (8).
#define TILE_BODY(T, VMSTR, STAGE_, PREF_)                                   \
  do {                                                                       \
    const char* rb = smem + ((T) & 3) * 32768;                               \
    const char* rbn = smem + (((T) + 1) & 3) * 32768;                        \
    char* lb = smem + (((T) + 3) & 3) * 32768;                               \
    if (STAGE_) {                                                            \
      gload_lds16(gA0, lb + ldA0);                                           \
      gload_lds16(gA1, lb + ldA1);                                           \
    }                                                                        \
    _Pragma("unroll")                                                        \
    for (int mi = 0; mi < 4; ++mi)                                           \
      ag[mi] = *(const short8*)(rb + aconst + (mi + 4) * 1024);              \
    SB0;                                                                     \
    __builtin_amdgcn_s_setprio(1);                                           \
    _Pragma("unroll")                                                        \
    for (int mi = 0; mi < 4; ++mi)                                           \
      _Pragma("unroll")                                                      \
      for (int ni = 0; ni < 4; ++ni)                                         \
        acc[mi][ni] = __builtin_amdgcn_mfma_f32_16x16x32_bf16(               \
            af[mi], bf_[ni], acc[mi][ni], 0, 0, 0);                          \
    __builtin_amdgcn_s_setprio(0);                                           \
    if (STAGE_) {                                                            \
      gload_lds16(gB0, lb + ldB0);                                           \
      gload_lds16(gB1, lb + ldB1);                                           \
      gA0 += 32; gA1 += 32; gB0 += 32; gB1 += 32;                            \
    }                                                                        \
    asm volatile("s_waitcnt vmcnt(" VMSTR ")" ::: "memory");                 \
    asm volatile("s_waitcnt lgkmcnt(0)" ::: "memory");                       \
    __builtin_amdgcn_s_barrier(); SB0;                                       \
    if (PREF_) {                                                             \
      _Pragma("unroll")                                                      \
      for (int mi = 0; mi < 4; ++mi)                                         \
        af[mi] = *(const short8*)(rbn + aconst + mi * 1024);                 \
    }                                                                        \
    SB0;                                                                     \
    __builtin_amdgcn_s_setprio(1);                                           \
    _Pragma("unroll")                                                        \
    for (int mi = 0; mi < 4; ++mi)                                           \
      _Pragma("unroll")                                                      \
      for (int ni = 0; ni < 4; ++ni)                                         \
        acc[mi + 4][ni] = __builtin_amdgcn_mfma_f32_16x16x32_bf16(           \
            ag[mi], bf_[ni], acc[mi + 4][ni], 0, 0, 0);                      \
    __builtin_amdgcn_s_setprio(0);                                           \
    if (PREF_) {                                                             \
      _Pragma("unroll")                                                      \
      for (int ni = 0; ni < 4; ++ni)                                         \
        bf_[ni] = *(const short8*)(rbn + bconst + ni * 1024);                \
    }                                                                        \
  } while (0)

  for (int t = 0; t < NKT - 3; ++t) TILE_BODY(t, "8", true, true);
  TILE_BODY(NKT - 3, "4", false, true);
  TILE_BODY(NKT - 2, "0", false, true);
  TILE_BODY(NKT - 1, "0", false, false);
#undef TILE_BODY

  // ---- fused LSTM epilogue ----
  // Wave-private 4.5KiB LDS bounce (stride 68 floats; bufs 0-1 region, final
  // K-tile read buf 3 -> untouched; waves only touch their own region).
  const int jw = fr;
  const int jg = tn * 64 + wc * 16 + jw;   // global j in [0,2048)
  const f32x4 bi = *(const f32x4*)(bias + tn * 256 + wc * 64 + jw * 4);
  float* ep = (float*)smem + wid * 1152;

#pragma unroll
  for (int mi = 0; mi < 8; ++mi) {
#pragma unroll
    for (int ni = 0; ni < 4; ++ni)
#pragma unroll
      for (int r = 0; r < 4; ++r)
        ep[(fq * 4 + r) * 68 + ni * 16 + fr] = acc[mi][ni][r];
    asm volatile("s_waitcnt lgkmcnt(0)" ::: "memory");
#pragma unroll
    for (int t4 = 0; t4 < 4; ++t4) {
      const int row = fq + t4 * 4;         // 0..15
      f32x4 g4 = *(const f32x4*)(ep + row * 68 + jw * 4);
      const float f_in = g4[0] + bi[0];
      const float i_in = g4[1] + bi[1];
      const float ic_in = g4[2] + bi[2];
      const float o_in = g4[3] + bi[3];
      const float ft = sigmoidf_(f_in);
      const float it = sigmoidf_(i_in);
      const float ics = __sinf(ic_in);
      const int mg = tm * 256 + wr * 128 + mi * 16 + row;
      const float cv = c[(size_t)mg * HDIM + jg];
      const float ct = cv * ft + ics * it;
      const float ot = sigmoidf_(o_in);
      const float ht = ot * __sinf(ct);
      out[(size_t)mg * HDIM + jg] = ht;
      out[OUT_HALF + (size_t)mg * HDIM + jg] = ct;
    }
    asm volatile("s_waitcnt lgkmcnt(0)" ::: "memory");
  }
}

extern "C" void kernel_launch(void* const* d_in, const int* in_sizes, int n_in,
                              void* d_out, int out_size, void* d_ws, size_t ws_size,
                              hipStream_t stream) {
  const float* x    = (const float*)d_in[0];
  const float* h    = (const float*)d_in[1];
  const float* c    = (const float*)d_in[2];
  const float* w_ih = (const float*)d_in[3];
  const float* w_hh = (const float*)d_in[4];
  const float* b_ih = (const float*)d_in[5];
  const float* b_hh = (const float*)d_in[6];
  float* out = (float*)d_out;

  char* ws = (char*)d_ws;
  unsigned short* Abf = (unsigned short*)ws;                       // 25,165,824 B
  unsigned short* Wbf = (unsigned short*)(ws + 25165824);          // 50,331,648 B
  float* bias = (float*)(ws + 25165824 + 50331648);                // 32,768 B

  hipFuncSetAttribute((const void*)lstm_gemm,
                      hipFuncAttributeMaxDynamicSharedMemorySize, 131072);

  pack_all<<<18432, 256, 0, stream>>>(x, h, w_ih, w_hh, b_ih, b_hh, Abf, Wbf, bias);
  lstm_gemm<<<512, 512, 131072, stream>>>(Abf, Wbf, bias, c, out);
}